// Round 10
// baseline (519.583 us; speedup 1.0000x reference)
//
#include <hip/hip_runtime.h>
#include <hip/hip_bf16.h>

#define BN_EPS 1e-5f

typedef __attribute__((ext_vector_type(8))) short bf16x8;
typedef __attribute__((ext_vector_type(4))) float f32x4;

__device__ __forceinline__ short f2b(float f) {
    __hip_bfloat16 h = __float2bfloat16(f);
    return *reinterpret_cast<short*>(&h);
}
__device__ __forceinline__ float bu2f(unsigned short u) {
    return __uint_as_float(((unsigned int)u) << 16);
}
__device__ __forceinline__ float lo16(unsigned int v) { return __uint_as_float(v << 16); }
__device__ __forceinline__ float hi16(unsigned int v) { return __uint_as_float(v & 0xffff0000u); }

#define DEG_SCALE 1048576.0f          /* 2^20 */
#define DEG_INV   (1.0f / 1048576.0f)
#define DEG_MASK  ((1ULL << 43) - 1)

// ---------------- int64-vs-int32 storage probe (one block) ----------------
__global__ void k_flag(const int* __restrict__ ei, int* __restrict__ flag) {
    __shared__ int any;
    if (threadIdx.x == 0) any = 0;
    __syncthreads();
    if (ei[2 * threadIdx.x + 1] != 0) atomicOr(&any, 1);
    __syncthreads();
    if (threadIdx.x == 0) *flag = (any == 0);  // all-high-words-zero => int64
}

// ---------------- histogram into 8 slot-local copies ----------------
__global__ void k_hist8(const int* __restrict__ ei, const float* __restrict__ ew,
                        const int* __restrict__ flag,
                        unsigned long long* __restrict__ packed8, int E, int N) {
    int e = blockIdx.x * blockDim.x + threadIdx.x;
    if (e >= E) return;
    int slot = blockIdx.x & 7;
    int d = (*flag) ? ei[2 * E + 2 * e] : ei[E + e];
    unsigned int wf = __float2uint_rn(ew[e] * DEG_SCALE);
    atomicAdd(&packed8[(size_t)slot * N + d], (1ULL << 43) | (unsigned long long)wf);
}

// ---------------- scan stage 1 fused with 8-copy merge + unpack ----------------
__global__ void k_scan1(const unsigned long long* __restrict__ packed8,
                        float* __restrict__ dinv, int* __restrict__ rowptr,
                        int* __restrict__ blktot, int N) {
    __shared__ int lds[256];
    int tid = threadIdx.x;
    int base = blockIdx.x * 1024 + tid * 4;
    int v[4]; int s = 0;
#pragma unroll
    for (int j = 0; j < 4; ++j) {
        int idx = base + j;
        if (idx < N) {
            unsigned long long ctot = 0, dtot = 0;
#pragma unroll
            for (int cpy = 0; cpy < 8; ++cpy) {
                unsigned long long p = packed8[(size_t)cpy * N + idx];
                ctot += p >> 43;
                dtot += p & DEG_MASK;
            }
            v[j] = (int)ctot;
            float deg = (float)dtot * DEG_INV;
            dinv[idx] = rsqrtf(deg + 1.0f);
        } else v[j] = 0;
        s += v[j];
    }
    lds[tid] = s;
    __syncthreads();
    for (int off = 1; off < 256; off <<= 1) {
        int t = (tid >= off) ? lds[tid - off] : 0;
        __syncthreads();
        lds[tid] += t;
        __syncthreads();
    }
    if (tid == 255) blktot[blockIdx.x] = lds[255];
    int run = lds[tid] - s;
#pragma unroll
    for (int j = 0; j < 4; ++j) {
        if (base + j < N) rowptr[base + j] = run;
        run += v[j];
    }
}

__global__ void k_scan2(int* blktot, int nb) {
    __shared__ int lds[256];
    int tid = threadIdx.x;
    int v = (tid < nb) ? blktot[tid] : 0;
    lds[tid] = v;
    __syncthreads();
    for (int off = 1; off < 256; off <<= 1) {
        int t = (tid >= off) ? lds[tid - off] : 0;
        __syncthreads();
        lds[tid] += t;
        __syncthreads();
    }
    if (tid < nb) blktot[tid] = lds[tid] - v;
}

__global__ void k_scan3(int* __restrict__ rowptr, const int* __restrict__ blktot,
                        int* __restrict__ cur, int N) {
    int i = blockIdx.x * blockDim.x + threadIdx.x;
    if (i < N) {
        int v = rowptr[i] + blktot[i >> 10];
        rowptr[i] = v;
        cur[i] = v;
    }
}

// ---------------- slot-chunked scatter ----------------
__global__ void k_scatter(const int* __restrict__ ei, const float* __restrict__ ew,
                          const int* __restrict__ flag, const float* __restrict__ dinv,
                          int* __restrict__ cur, int2* __restrict__ ecsr, int E, int N) {
    int slot = blockIdx.x & 7;
    int chunk = blockIdx.x >> 3;
    int e = chunk * 256 + threadIdx.x;
    if (e >= E) return;
    int d = (*flag) ? ei[2 * E + 2 * e] : ei[E + e];
    int N8 = (N + 7) >> 3;
    int lo = slot * N8;
    if (d < lo || d >= lo + N8) return;
    int s = (*flag) ? ei[2 * e] : ei[e];
    int pos = atomicAdd(&cur[d], 1);
    int2 rec;
    rec.x = s;
    rec.y = __float_as_int(dinv[s] * ew[e] * dinv[d]);
    ecsr[pos] = rec;
}

// ---------------- weight transpose (bf16) + x -> bf16 table ----------------
__global__ void k_prep_wt(const float* __restrict__ W1, const float* __restrict__ W2,
                          const float* __restrict__ Wm, short* __restrict__ w1t,
                          short* __restrict__ w2t, short* __restrict__ wmt) {
    int idx = blockIdx.x * 256 + threadIdx.x;
    if (idx < 128 * 64) {
        int c = idx >> 6, k = idx & 63;
        w1t[idx] = f2b(W1[k * 128 + c]);
    } else if (idx < 128 * 64 + 128 * 128) {
        int i = idx - 128 * 64; int c = i >> 7, k = i & 127;
        w2t[i] = f2b(W2[k * 128 + c]);
    } else if (idx < 128 * 64 + 128 * 128 + 128 * 384) {
        int i = idx - (128 * 64 + 128 * 128); int c = i / 384, k = i % 384;
        wmt[i] = f2b(Wm[k * 128 + c]);
    }
}

__global__ void k_prep_xb(const float* __restrict__ x, unsigned short* __restrict__ xb,
                          int total4) {
    int i = blockIdx.x * blockDim.x + threadIdx.x;  // total4 = N*16
    if (i >= total4) return;
    float4 v = ((const float4*)x)[i];
    ushort4 o;
    o.x = (unsigned short)f2b(v.x);
    o.y = (unsigned short)f2b(v.y);
    o.z = (unsigned short)f2b(v.z);
    o.w = (unsigned short)f2b(v.w);
    ((ushort4*)xb)[i] = o;
}

// ---------------- LDS-free direct-fragment MFMA GEMM ----------------
// Fragments for mfma_16x16x32_bf16 are 16B-contiguous in row-major bf16:
//   A-frag: A[row + (lane&15)][k0 + (lane>>4)*8 .. +8]
//   B-frag: Bt[col][k0 ..] likewise -> no LDS staging, no K-loop barriers.
// Block = 4 waves; wave w owns rows [r0+32w, +32) x all 128 cols (acc[2][8]).
// MODE 0: K=64  A=agg0 bf16; out bf16 + bias eb (b1); fused BN stats -> stats
// MODE 1: K=128 A=h1c bf16 + BN(stats,g,be)+ReLU in-reg; out bf16
// MODE 2: K=384 virtual (BN2ReLU(h2c) | dist-feat | degf-feat); out f32 + bias eb (bm)
template <int K, int MODE>
__global__ __launch_bounds__(256) void k_gemm(
        const unsigned short* __restrict__ A, const short* __restrict__ Bt,
        float* __restrict__ stats, const float* __restrict__ g,
        const float* __restrict__ be, const float* __restrict__ dist,
        const float* __restrict__ degf, const float* __restrict__ Wd,
        const float* __restrict__ bd, const float* __restrict__ Wg,
        const float* __restrict__ bg, const float* __restrict__ eb,
        void* __restrict__ out, int N, float invN) {
    __shared__ float sc[128], sh[128];
    __shared__ float st0[128], st1[128];
    const int t = threadIdx.x;
    const int lane = t & 63;
    const int wave = t >> 6;
    const int rl = lane & 15;
    const int kg = lane >> 4;
    const int r0 = blockIdx.x * 128;

    if (MODE >= 1) {
        if (t < 128) {
            float mean = stats[t] * invN;
            float var = stats[128 + t] * invN - mean * mean;
            float scale = g[t] * rsqrtf(var + BN_EPS);
            sc[t] = scale;
            sh[t] = be[t] - mean * scale;
        }
        __syncthreads();
    }
    if (MODE == 0) {
        if (t < 128) { st0[t] = 0.f; st1[t] = 0.f; }
        __syncthreads();
    }

    f32x4 acc[2][8];
#pragma unroll
    for (int m = 0; m < 2; ++m)
#pragma unroll
        for (int n = 0; n < 8; ++n) acc[m][n] = (f32x4){0.f, 0.f, 0.f, 0.f};

    const int AST = (MODE == 0) ? 64 : 128;
    const int rowbase = r0 + wave * 32 + rl;

    for (int kt = 0; kt < K; kt += 32) {
        const int k0 = kt + kg * 8;
        bf16x8 a[2];
#pragma unroll
        for (int m = 0; m < 2; ++m) {
            const int row = rowbase + m * 16;
            union { int4 q; unsigned short s[8]; } u;
            if (MODE == 2 && kt >= 128) {
                if (row < N) {
                    const float* Wv; const float* bv; float sx; int cb;
                    if (kt >= 256) { Wv = Wg; bv = bg; sx = degf[row]; cb = k0 - 256; }
                    else           { Wv = Wd; bv = bd; sx = dist[row]; cb = k0 - 128; }
#pragma unroll
                    for (int j = 0; j < 8; ++j)
                        u.s[j] = (unsigned short)f2b(fmaxf(0.f, sx * Wv[cb + j] + bv[cb + j]));
                } else u.q = (int4){0, 0, 0, 0};
            } else if (MODE == 0) {
                u.q = (row < N) ? *(const int4*)(A + (size_t)row * AST + k0)
                                : (int4){0, 0, 0, 0};
            } else {  // MODE 1, or MODE 2 kt<128: BN + ReLU in registers
                if (row < N) {
                    union { int4 q; unsigned short s[8]; } raw;
                    raw.q = *(const int4*)(A + (size_t)row * AST + k0);
#pragma unroll
                    for (int j = 0; j < 8; ++j)
                        u.s[j] = (unsigned short)f2b(
                            fmaxf(0.f, bu2f(raw.s[j]) * sc[k0 + j] + sh[k0 + j]));
                } else u.q = (int4){0, 0, 0, 0};
            }
            a[m] = *reinterpret_cast<bf16x8*>(&u);
        }
#pragma unroll
        for (int n = 0; n < 8; ++n) {
            bf16x8 b = *reinterpret_cast<const bf16x8*>(&Bt[(size_t)(n * 16 + rl) * K + k0]);
            acc[0][n] = __builtin_amdgcn_mfma_f32_16x16x32_bf16(a[0], b, acc[0][n], 0, 0, 0);
            acc[1][n] = __builtin_amdgcn_mfma_f32_16x16x32_bf16(a[1], b, acc[1][n], 0, 0, 0);
        }
    }

    // epilogue (C/D: col=lane&15, row=(lane>>4)*4+reg; m89-verified)
    const int rbase = r0 + wave * 32 + kg * 4;
#pragma unroll
    for (int n = 0; n < 8; ++n) {
        int col = n * 16 + rl;
        float bias = (MODE != 1) ? eb[col] : 0.f;
        float sl = 0.f, ql = 0.f;
#pragma unroll
        for (int m = 0; m < 2; ++m) {
#pragma unroll
            for (int j = 0; j < 4; ++j) {
                int row = rbase + m * 16 + j;
                if (row < N) {
                    float val = acc[m][n][j] + bias;
                    if (MODE == 2) ((float*)out)[(size_t)row * 128 + col] = val;
                    else ((unsigned short*)out)[(size_t)row * 128 + col] = (unsigned short)f2b(val);
                    if (MODE == 0) { sl += val; ql += val * val; }
                }
            }
        }
        if (MODE == 0) {
            atomicAdd(&st0[col], sl);
            atomicAdd(&st1[col], ql);
        }
    }
    if (MODE == 0) {
        __syncthreads();
        if (t < 128) {
            atomicAdd(&stats[t], st0[t]);
            atomicAdd(&stats[128 + t], st1[t]);
        }
    }
}

// ---------------- CSR gathers (unroll x8) ----------------
__global__ void k_gather64(const unsigned short* __restrict__ xb, const int2* __restrict__ ecsr,
                           const int* __restrict__ rowptr, const int* __restrict__ rowend,
                           const float* __restrict__ dinv, unsigned short* __restrict__ agg0,
                           int N) {
    int node = blockIdx.x * 4 + (threadIdx.x >> 6);
    if (node >= N) return;
    int lane = threadIdx.x & 63;
    int start = rowptr[node], end = rowend[node];
    float di = dinv[node];
    float ax = di * di * bu2f(xb[(size_t)node * 64 + lane]);
    int j = start;
    for (; j + 8 <= end; j += 8) {
        float a0 = 0.f, a1 = 0.f;
#pragma unroll
        for (int u = 0; u < 8; u += 2) {
            int2 ea = ecsr[j + u], eb2 = ecsr[j + u + 1];
            a0 += __int_as_float(ea.y)  * bu2f(xb[(size_t)ea.x  * 64 + lane]);
            a1 += __int_as_float(eb2.y) * bu2f(xb[(size_t)eb2.x * 64 + lane]);
        }
        ax += a0 + a1;
    }
    for (; j < end; ++j) {
        int2 e = ecsr[j];
        ax += __int_as_float(e.y) * bu2f(xb[(size_t)e.x * 64 + lane]);
    }
    agg0[(size_t)node * 64 + lane] = (unsigned short)f2b(ax);
}

__global__ void k_gather128b(const unsigned int* __restrict__ t2, const int2* __restrict__ ecsr,
                             const int* __restrict__ rowptr, const int* __restrict__ rowend,
                             const float* __restrict__ dinv, const float* __restrict__ bias,
                             unsigned int* __restrict__ h2c, int N) {
    int node = blockIdx.x * 4 + (threadIdx.x >> 6);
    if (node >= N) return;
    int lane = threadIdx.x & 63;
    int start = rowptr[node], end = rowend[node];
    float di = dinv[node];
    float sl = di * di;
    unsigned int hv = t2[(size_t)node * 64 + lane];
    float2 bv = ((const float2*)bias)[lane];
    float ax = sl * lo16(hv) + bv.x;
    float ay = sl * hi16(hv) + bv.y;
    int j = start;
    for (; j + 8 <= end; j += 8) {
        int2 e[8]; unsigned int v[8];
#pragma unroll
        for (int u = 0; u < 8; ++u) e[u] = ecsr[j + u];
#pragma unroll
        for (int u = 0; u < 8; ++u) v[u] = t2[(size_t)e[u].x * 64 + lane];
#pragma unroll
        for (int u = 0; u < 8; ++u) {
            float w = __int_as_float(e[u].y);
            ax += w * lo16(v[u]);
            ay += w * hi16(v[u]);
        }
    }
    for (; j < end; ++j) {
        int2 e = ecsr[j];
        float w = __int_as_float(e.y);
        unsigned int v = t2[(size_t)e.x * 64 + lane];
        ax += w * lo16(v);
        ay += w * hi16(v);
    }
    unsigned int packed = (unsigned int)(unsigned short)f2b(ax) |
                          ((unsigned int)(unsigned short)f2b(ay) << 16);
    h2c[(size_t)node * 64 + lane] = packed;
}

// ---------------- BN2 stats: vectorized partials + final reduce ----------------
__global__ __launch_bounds__(256) void k_bn_partial(const uint4* __restrict__ h,
                                                    float* __restrict__ part, int total4) {
    __shared__ float sm[256];
    sm[threadIdx.x] = 0.f;
    __syncthreads();
    float s[8], q[8];
#pragma unroll
    for (int j = 0; j < 8; ++j) { s[j] = 0.f; q[j] = 0.f; }
    int stride = gridDim.x * 256;
    for (int i = blockIdx.x * 256 + threadIdx.x; i < total4; i += stride) {
        uint4 v = h[i];
        float a;
        a = lo16(v.x); s[0] += a; q[0] += a * a;
        a = hi16(v.x); s[1] += a; q[1] += a * a;
        a = lo16(v.y); s[2] += a; q[2] += a * a;
        a = hi16(v.y); s[3] += a; q[3] += a * a;
        a = lo16(v.z); s[4] += a; q[4] += a * a;
        a = hi16(v.z); s[5] += a; q[5] += a * a;
        a = lo16(v.w); s[6] += a; q[6] += a * a;
        a = hi16(v.w); s[7] += a; q[7] += a * a;
    }
    int c0 = 8 * (threadIdx.x & 15);
#pragma unroll
    for (int j = 0; j < 8; ++j) {
        atomicAdd(&sm[c0 + j], s[j]);
        atomicAdd(&sm[128 + c0 + j], q[j]);
    }
    __syncthreads();
    part[blockIdx.x * 256 + threadIdx.x] = sm[threadIdx.x];
}

__global__ void k_bn_reduce(const float* __restrict__ part, float* __restrict__ stats, int nb) {
    int t = threadIdx.x;
    float acc = 0.f;
#pragma unroll 4
    for (int b = 0; b < nb; ++b) acc += part[b * 256 + t];
    stats[t] = acc;
}

extern "C" void kernel_launch(void* const* d_in, const int* in_sizes, int n_in,
                              void* d_out, int out_size, void* d_ws, size_t ws_size,
                              hipStream_t stream) {
    const float* x    = (const float*)d_in[0];
    const int*   ei   = (const int*)d_in[1];
    const float* ew   = (const float*)d_in[2];
    const float* dist = (const float*)d_in[3];
    const float* degf = (const float*)d_in[4];
    const float* W1   = (const float*)d_in[5];
    const float* b1   = (const float*)d_in[6];
    const float* W2   = (const float*)d_in[7];
    const float* b2   = (const float*)d_in[8];
    const float* g1   = (const float*)d_in[9];
    const float* be1  = (const float*)d_in[10];
    const float* g2   = (const float*)d_in[11];
    const float* be2  = (const float*)d_in[12];
    const float* Wd   = (const float*)d_in[13];
    const float* bd   = (const float*)d_in[14];
    const float* Wg   = (const float*)d_in[15];
    const float* bg   = (const float*)d_in[16];
    const float* Wm   = (const float*)d_in[17];
    const float* bm   = (const float*)d_in[18];

    const int IN = 64;
    const int N = in_sizes[0] / IN;   // 100000
    const int E = in_sizes[1] / 2;    // 1600000

    // ws layout (4B words):
    unsigned long long* packed8 = (unsigned long long*)d_ws;         // [8][N] u64
    float* stats  = (float*)d_ws + 16 * (size_t)N;
    int*   flag   = (int*)(stats + 512);
    int*   rowptr = flag + 128;
    int*   cur    = rowptr + N;
    float* dinv   = (float*)(cur + N);
    int*   blktot = (int*)(dinv + N);
    int2*  ecsr   = (int2*)(blktot + 256);
    unsigned int*   h2c  = (unsigned int*)(ecsr + E);                // N*128 bf16
    unsigned short* agg0 = (unsigned short*)(h2c + (size_t)N * 64);  // N*64 bf16
    unsigned short* xb   = agg0 + (size_t)N * 64;                    // N*64 bf16
    short* w1t    = (short*)(xb + (size_t)N * 64);                   // [128][64]
    short* w2t    = w1t + 128 * 64;                                  // [128][128]
    short* wmt    = w2t + 128 * 128;                                 // [128][384]
    float* part   = (float*)(wmt + 128 * 384);                       // [512][256]

    // d_out time-share (bf16 staging, overwritten by final f32 GEMM)
    unsigned short* h1c = (unsigned short*)d_out;                    // N*128 bf16
    unsigned int*   t2  = (unsigned int*)d_out + (size_t)N * 64;     // N*128 bf16 pairs

    hipMemsetAsync(packed8, 0, (16 * (size_t)N + 512) * sizeof(float), stream);

    const int nbE = (E + 255) / 256;
    const int nbN = (N + 255) / 256;
    const int nscan = (N + 1023) / 1024;

    k_flag<<<1, 256, 0, stream>>>(ei, flag);
    k_prep_wt<<<288, 256, 0, stream>>>(W1, W2, Wm, w1t, w2t, wmt);
    k_prep_xb<<<(N * 16 + 255) / 256, 256, 0, stream>>>(x, xb, N * 16);
    k_hist8<<<nbE, 256, 0, stream>>>(ei, ew, flag, packed8, E, N);
    k_scan1<<<nscan, 256, 0, stream>>>(packed8, dinv, rowptr, blktot, N);
    k_scan2<<<1, 256, 0, stream>>>(blktot, nscan);
    k_scan3<<<nbN, 256, 0, stream>>>(rowptr, blktot, cur, N);
    k_scatter<<<nbE * 8, 256, 0, stream>>>(ei, ew, flag, dinv, cur, ecsr, E, N);

    const int nbGe = (N + 127) / 128;
    const int nbG  = (N + 3) / 4;
    const int nbP  = 512;
    const float invN = 1.0f / (float)N;

    // layer 1: agg0 = A_hat @ x; h1c = agg0 @ W1 + b1 (stats1 fused in epilogue)
    k_gather64<<<nbG, 256, 0, stream>>>(xb, ecsr, rowptr, cur, dinv, agg0, N);
    k_gemm<64, 0><<<nbGe, 256, 0, stream>>>(agg0, w1t, stats, nullptr, nullptr, nullptr,
                                            nullptr, nullptr, nullptr, nullptr, nullptr,
                                            b1, h1c, N, invN);

    // layer 2: t2 = BN1ReLU(h1c) @ W2; h2c = A_hat @ t2 + b2; stats2 (two-stage)
    k_gemm<128, 1><<<nbGe, 256, 0, stream>>>(h1c, w2t, stats, g1, be1, nullptr,
                                             nullptr, nullptr, nullptr, nullptr, nullptr,
                                             nullptr, t2, N, invN);
    k_gather128b<<<nbG, 256, 0, stream>>>(t2, ecsr, rowptr, cur, dinv, b2, h2c, N);
    k_bn_partial<<<nbP, 256, 0, stream>>>((const uint4*)h2c, part, N * 16);
    k_bn_reduce<<<1, 256, 0, stream>>>(part, stats + 256, nbP);

    // final: [BN2ReLU(h2c) | relu(dist*Wd+bd) | relu(degf*Wg+bg)] @ Wm + bm -> d_out f32
    k_gemm<384, 2><<<nbGe, 256, 0, stream>>>((const unsigned short*)h2c, wmt, stats + 256,
                                             g2, be2, dist, degf, Wd, bd, Wg, bg,
                                             bm, d_out, N, invN);
}

// Round 11
// 477.478 us; speedup vs baseline: 1.0882x; 1.0882x over previous
//
#include <hip/hip_runtime.h>
#include <hip/hip_bf16.h>

#define BN_EPS 1e-5f

typedef __attribute__((ext_vector_type(8))) short bf16x8;
typedef __attribute__((ext_vector_type(4))) float f32x4;

__device__ __forceinline__ short f2b(float f) {
    __hip_bfloat16 h = __float2bfloat16(f);
    return *reinterpret_cast<short*>(&h);
}
__device__ __forceinline__ float bu2f(unsigned short u) {
    return __uint_as_float(((unsigned int)u) << 16);
}
__device__ __forceinline__ float lo16(unsigned int v) { return __uint_as_float(v << 16); }
__device__ __forceinline__ float hi16(unsigned int v) { return __uint_as_float(v & 0xffff0000u); }

#define DEG_SCALE 1048576.0f          /* 2^20 */
#define DEG_INV   (1.0f / 1048576.0f)
#define DEG_MASK  ((1ULL << 43) - 1)

// ---------------- int64-vs-int32 storage probe (one block) ----------------
__global__ void k_flag(const int* __restrict__ ei, int* __restrict__ flag) {
    __shared__ int any;
    if (threadIdx.x == 0) any = 0;
    __syncthreads();
    if (ei[2 * threadIdx.x + 1] != 0) atomicOr(&any, 1);
    __syncthreads();
    if (threadIdx.x == 0) *flag = (any == 0);  // all-high-words-zero => int64
}

// ---------------- histogram into 8 slot-local copies ----------------
__global__ void k_hist8(const int* __restrict__ ei, const float* __restrict__ ew,
                        const int* __restrict__ flag,
                        unsigned long long* __restrict__ packed8, int E, int N) {
    int e = blockIdx.x * blockDim.x + threadIdx.x;
    if (e >= E) return;
    int slot = blockIdx.x & 7;
    int d = (*flag) ? ei[2 * E + 2 * e] : ei[E + e];
    unsigned int wf = __float2uint_rn(ew[e] * DEG_SCALE);
    atomicAdd(&packed8[(size_t)slot * N + d], (1ULL << 43) | (unsigned long long)wf);
}

// ---------------- scan stage 1 fused with 8-copy merge + unpack ----------------
__global__ void k_scan1(const unsigned long long* __restrict__ packed8,
                        float* __restrict__ dinv, int* __restrict__ rowptr,
                        int* __restrict__ blktot, int N) {
    __shared__ int lds[256];
    int tid = threadIdx.x;
    int base = blockIdx.x * 1024 + tid * 4;
    int v[4]; int s = 0;
#pragma unroll
    for (int j = 0; j < 4; ++j) {
        int idx = base + j;
        if (idx < N) {
            unsigned long long ctot = 0, dtot = 0;
#pragma unroll
            for (int cpy = 0; cpy < 8; ++cpy) {
                unsigned long long p = packed8[(size_t)cpy * N + idx];
                ctot += p >> 43;
                dtot += p & DEG_MASK;
            }
            v[j] = (int)ctot;
            float deg = (float)dtot * DEG_INV;
            dinv[idx] = rsqrtf(deg + 1.0f);
        } else v[j] = 0;
        s += v[j];
    }
    lds[tid] = s;
    __syncthreads();
    for (int off = 1; off < 256; off <<= 1) {
        int t = (tid >= off) ? lds[tid - off] : 0;
        __syncthreads();
        lds[tid] += t;
        __syncthreads();
    }
    if (tid == 255) blktot[blockIdx.x] = lds[255];
    int run = lds[tid] - s;
#pragma unroll
    for (int j = 0; j < 4; ++j) {
        if (base + j < N) rowptr[base + j] = run;
        run += v[j];
    }
}

__global__ void k_scan2(int* blktot, int nb) {
    __shared__ int lds[256];
    int tid = threadIdx.x;
    int v = (tid < nb) ? blktot[tid] : 0;
    lds[tid] = v;
    __syncthreads();
    for (int off = 1; off < 256; off <<= 1) {
        int t = (tid >= off) ? lds[tid - off] : 0;
        __syncthreads();
        lds[tid] += t;
        __syncthreads();
    }
    if (tid < nb) blktot[tid] = lds[tid] - v;
}

__global__ void k_scan3(int* __restrict__ rowptr, const int* __restrict__ blktot,
                        int* __restrict__ cur, int N) {
    int i = blockIdx.x * blockDim.x + threadIdx.x;
    if (i < N) {
        int v = rowptr[i] + blktot[i >> 10];
        rowptr[i] = v;
        cur[i] = v;
    }
}

// ---------------- slot-chunked scatter ----------------
__global__ void k_scatter(const int* __restrict__ ei, const float* __restrict__ ew,
                          const int* __restrict__ flag, const float* __restrict__ dinv,
                          int* __restrict__ cur, int2* __restrict__ ecsr, int E, int N) {
    int slot = blockIdx.x & 7;
    int chunk = blockIdx.x >> 3;
    int e = chunk * 256 + threadIdx.x;
    if (e >= E) return;
    int d = (*flag) ? ei[2 * E + 2 * e] : ei[E + e];
    int N8 = (N + 7) >> 3;
    int lo = slot * N8;
    if (d < lo || d >= lo + N8) return;
    int s = (*flag) ? ei[2 * e] : ei[e];
    int pos = atomicAdd(&cur[d], 1);
    int2 rec;
    rec.x = s;
    rec.y = __float_as_int(dinv[s] * ew[e] * dinv[d]);
    ecsr[pos] = rec;
}

// ---------------- weight transpose (bf16) + x -> bf16 table ----------------
__global__ void k_prep_wt(const float* __restrict__ W1, const float* __restrict__ W2,
                          const float* __restrict__ Wm, short* __restrict__ w1t,
                          short* __restrict__ w2t, short* __restrict__ wmt) {
    int idx = blockIdx.x * 256 + threadIdx.x;
    if (idx < 128 * 64) {
        int c = idx >> 6, k = idx & 63;
        w1t[idx] = f2b(W1[k * 128 + c]);
    } else if (idx < 128 * 64 + 128 * 128) {
        int i = idx - 128 * 64; int c = i >> 7, k = i & 127;
        w2t[i] = f2b(W2[k * 128 + c]);
    } else if (idx < 128 * 64 + 128 * 128 + 128 * 384) {
        int i = idx - (128 * 64 + 128 * 128); int c = i / 384, k = i % 384;
        wmt[i] = f2b(Wm[k * 128 + c]);
    }
}

__global__ void k_prep_xb(const float* __restrict__ x, unsigned short* __restrict__ xb,
                          int total4) {
    int i = blockIdx.x * blockDim.x + threadIdx.x;  // total4 = N*16
    if (i >= total4) return;
    float4 v = ((const float4*)x)[i];
    ushort4 o;
    o.x = (unsigned short)f2b(v.x);
    o.y = (unsigned short)f2b(v.y);
    o.z = (unsigned short)f2b(v.z);
    o.w = (unsigned short)f2b(v.w);
    ((ushort4*)xb)[i] = o;
}

// ---------------- hybrid MFMA GEMM: B staged in LDS per 128-K chunk, A direct ----------------
// A-frag (16B contiguous in row-major bf16): A[row + (lane&15)][k0 + (lane>>4)*8 ..+8]
// B staged to LDS once per CH=min(K,128) chunk (rows padded +8 shorts -> 2-way bank alias, free).
// Block = 4 waves x 32 rows = 128 rows, each wave all 128 cols (acc[2][8]).
// MODE 0: K=64  A=agg0 bf16; out bf16 + bias eb (b1); fused BN stats -> stats
// MODE 1: K=128 A=h1c bf16 + BN(stats,g,be)+ReLU in-reg; out bf16
// MODE 2: K=384 virtual (BN2ReLU(h2c) | dist-feat | degf-feat); out f32 + bias eb (bm)
template <int K, int MODE>
__global__ __launch_bounds__(256) void k_gemm(
        const unsigned short* __restrict__ A, const short* __restrict__ Bt,
        float* __restrict__ stats, const float* __restrict__ g,
        const float* __restrict__ be, const float* __restrict__ dist,
        const float* __restrict__ degf, const float* __restrict__ Wd,
        const float* __restrict__ bd, const float* __restrict__ Wg,
        const float* __restrict__ bg, const float* __restrict__ eb,
        void* __restrict__ out, int N, float invN) {
    constexpr int CH = (K < 128) ? K : 128;   // B chunk size along k
    __shared__ short Bs[128][CH + 8];
    __shared__ float sc[128], sh[128];
    __shared__ float st0[128], st1[128];
    const int t = threadIdx.x;
    const int lane = t & 63;
    const int wave = t >> 6;
    const int rl = lane & 15;
    const int kg = lane >> 4;
    const int r0 = blockIdx.x * 128;

    if (MODE >= 1) {
        if (t < 128) {
            float mean = stats[t] * invN;
            float var = stats[128 + t] * invN - mean * mean;
            float scale = g[t] * rsqrtf(var + BN_EPS);
            sc[t] = scale;
            sh[t] = be[t] - mean * scale;
        }
    }
    if (MODE == 0) {
        if (t < 128) { st0[t] = 0.f; st1[t] = 0.f; }
    }

    f32x4 acc[2][8];
#pragma unroll
    for (int m = 0; m < 2; ++m)
#pragma unroll
        for (int n = 0; n < 8; ++n) acc[m][n] = (f32x4){0.f, 0.f, 0.f, 0.f};

    const int AST = (MODE == 0) ? 64 : 128;
    const int rowbase = r0 + wave * 32 + rl;

    for (int kc = 0; kc < K; kc += CH) {
        if (kc > 0) __syncthreads();   // protect Bs reuse
        // ---- stage B chunk: col = t>>1, half = t&1 handles CH/2 shorts ----
        {
            int c = t >> 1;
            int hb = (t & 1) * (CH / 2);
            const short* wrow = Bt + (size_t)c * K + kc + hb;
#pragma unroll
            for (int q = 0; q < CH / 16; ++q)
                *(int4*)&Bs[c][hb + q * 8] = ((const int4*)wrow)[q];
        }
        __syncthreads();
        // ---- K-steps within chunk: A direct from global, B from LDS, no barriers ----
#pragma unroll
        for (int kt0 = 0; kt0 < CH; kt0 += 32) {
            const int kt = kc + kt0;
            const int k0 = kt + kg * 8;    // global k for A
            const int kl0 = kt0 + kg * 8;  // LDS k for B
            bf16x8 a[2];
#pragma unroll
            for (int m = 0; m < 2; ++m) {
                const int row = rowbase + m * 16;
                union { int4 q; unsigned short s[8]; } u;
                if (MODE == 2 && kt >= 128) {
                    if (row < N) {
                        const float* Wv; const float* bv; float sx; int cb;
                        if (kt >= 256) { Wv = Wg; bv = bg; sx = degf[row]; cb = k0 - 256; }
                        else           { Wv = Wd; bv = bd; sx = dist[row]; cb = k0 - 128; }
#pragma unroll
                        for (int j = 0; j < 8; ++j)
                            u.s[j] = (unsigned short)f2b(fmaxf(0.f, sx * Wv[cb + j] + bv[cb + j]));
                    } else u.q = (int4){0, 0, 0, 0};
                } else if (MODE == 0) {
                    u.q = (row < N) ? *(const int4*)(A + (size_t)row * AST + k0)
                                    : (int4){0, 0, 0, 0};
                } else {  // MODE 1, or MODE 2 kt<128: BN + ReLU in registers
                    if (row < N) {
                        union { int4 q; unsigned short s[8]; } raw;
                        raw.q = *(const int4*)(A + (size_t)row * AST + k0);
#pragma unroll
                        for (int j = 0; j < 8; ++j)
                            u.s[j] = (unsigned short)f2b(
                                fmaxf(0.f, bu2f(raw.s[j]) * sc[k0 + j] + sh[k0 + j]));
                    } else u.q = (int4){0, 0, 0, 0};
                }
                a[m] = *reinterpret_cast<bf16x8*>(&u);
            }
#pragma unroll
            for (int n = 0; n < 8; ++n) {
                bf16x8 b = *reinterpret_cast<const bf16x8*>(&Bs[n * 16 + rl][kl0]);
                acc[0][n] = __builtin_amdgcn_mfma_f32_16x16x32_bf16(a[0], b, acc[0][n], 0, 0, 0);
                acc[1][n] = __builtin_amdgcn_mfma_f32_16x16x32_bf16(a[1], b, acc[1][n], 0, 0, 0);
            }
        }
    }

    // epilogue (C/D: col=lane&15, row=(lane>>4)*4+reg; m89-verified)
    const int rbase = r0 + wave * 32 + kg * 4;
#pragma unroll
    for (int n = 0; n < 8; ++n) {
        int col = n * 16 + rl;
        float bias = (MODE != 1) ? eb[col] : 0.f;
        float sl = 0.f, ql = 0.f;
#pragma unroll
        for (int m = 0; m < 2; ++m) {
#pragma unroll
            for (int j = 0; j < 4; ++j) {
                int row = rbase + m * 16 + j;
                if (row < N) {
                    float val = acc[m][n][j] + bias;
                    if (MODE == 2) ((float*)out)[(size_t)row * 128 + col] = val;
                    else ((unsigned short*)out)[(size_t)row * 128 + col] = (unsigned short)f2b(val);
                    if (MODE == 0) { sl += val; ql += val * val; }
                }
            }
        }
        if (MODE == 0) {
            atomicAdd(&st0[col], sl);
            atomicAdd(&st1[col], ql);
        }
    }
    if (MODE == 0) {
        __syncthreads();
        if (t < 128) {
            atomicAdd(&stats[t], st0[t]);
            atomicAdd(&stats[128 + t], st1[t]);
        }
    }
}

// ---------------- CSR gathers (unroll x8) ----------------
__global__ void k_gather64(const unsigned short* __restrict__ xb, const int2* __restrict__ ecsr,
                           const int* __restrict__ rowptr, const int* __restrict__ rowend,
                           const float* __restrict__ dinv, unsigned short* __restrict__ agg0,
                           int N) {
    int node = blockIdx.x * 4 + (threadIdx.x >> 6);
    if (node >= N) return;
    int lane = threadIdx.x & 63;
    int start = rowptr[node], end = rowend[node];
    float di = dinv[node];
    float ax = di * di * bu2f(xb[(size_t)node * 64 + lane]);
    int j = start;
    for (; j + 8 <= end; j += 8) {
        float a0 = 0.f, a1 = 0.f;
#pragma unroll
        for (int u = 0; u < 8; u += 2) {
            int2 ea = ecsr[j + u], eb2 = ecsr[j + u + 1];
            a0 += __int_as_float(ea.y)  * bu2f(xb[(size_t)ea.x  * 64 + lane]);
            a1 += __int_as_float(eb2.y) * bu2f(xb[(size_t)eb2.x * 64 + lane]);
        }
        ax += a0 + a1;
    }
    for (; j < end; ++j) {
        int2 e = ecsr[j];
        ax += __int_as_float(e.y) * bu2f(xb[(size_t)e.x * 64 + lane]);
    }
    agg0[(size_t)node * 64 + lane] = (unsigned short)f2b(ax);
}

__global__ void k_gather128b(const unsigned int* __restrict__ t2, const int2* __restrict__ ecsr,
                             const int* __restrict__ rowptr, const int* __restrict__ rowend,
                             const float* __restrict__ dinv, const float* __restrict__ bias,
                             unsigned int* __restrict__ h2c, int N) {
    int node = blockIdx.x * 4 + (threadIdx.x >> 6);
    if (node >= N) return;
    int lane = threadIdx.x & 63;
    int start = rowptr[node], end = rowend[node];
    float di = dinv[node];
    float sl = di * di;
    unsigned int hv = t2[(size_t)node * 64 + lane];
    float2 bv = ((const float2*)bias)[lane];
    float ax = sl * lo16(hv) + bv.x;
    float ay = sl * hi16(hv) + bv.y;
    int j = start;
    for (; j + 8 <= end; j += 8) {
        int2 e[8]; unsigned int v[8];
#pragma unroll
        for (int u = 0; u < 8; ++u) e[u] = ecsr[j + u];
#pragma unroll
        for (int u = 0; u < 8; ++u) v[u] = t2[(size_t)e[u].x * 64 + lane];
#pragma unroll
        for (int u = 0; u < 8; ++u) {
            float w = __int_as_float(e[u].y);
            ax += w * lo16(v[u]);
            ay += w * hi16(v[u]);
        }
    }
    for (; j < end; ++j) {
        int2 e = ecsr[j];
        float w = __int_as_float(e.y);
        unsigned int v = t2[(size_t)e.x * 64 + lane];
        ax += w * lo16(v);
        ay += w * hi16(v);
    }
    unsigned int packed = (unsigned int)(unsigned short)f2b(ax) |
                          ((unsigned int)(unsigned short)f2b(ay) << 16);
    h2c[(size_t)node * 64 + lane] = packed;
}

// ---------------- BN2 stats: vectorized partials + final reduce ----------------
__global__ __launch_bounds__(256) void k_bn_partial(const uint4* __restrict__ h,
                                                    float* __restrict__ part, int total4) {
    __shared__ float sm[256];
    sm[threadIdx.x] = 0.f;
    __syncthreads();
    float s[8], q[8];
#pragma unroll
    for (int j = 0; j < 8; ++j) { s[j] = 0.f; q[j] = 0.f; }
    int stride = gridDim.x * 256;
    for (int i = blockIdx.x * 256 + threadIdx.x; i < total4; i += stride) {
        uint4 v = h[i];
        float a;
        a = lo16(v.x); s[0] += a; q[0] += a * a;
        a = hi16(v.x); s[1] += a; q[1] += a * a;
        a = lo16(v.y); s[2] += a; q[2] += a * a;
        a = hi16(v.y); s[3] += a; q[3] += a * a;
        a = lo16(v.z); s[4] += a; q[4] += a * a;
        a = hi16(v.z); s[5] += a; q[5] += a * a;
        a = lo16(v.w); s[6] += a; q[6] += a * a;
        a = hi16(v.w); s[7] += a; q[7] += a * a;
    }
    int c0 = 8 * (threadIdx.x & 15);
#pragma unroll
    for (int j = 0; j < 8; ++j) {
        atomicAdd(&sm[c0 + j], s[j]);
        atomicAdd(&sm[128 + c0 + j], q[j]);
    }
    __syncthreads();
    part[blockIdx.x * 256 + threadIdx.x] = sm[threadIdx.x];
}

__global__ void k_bn_reduce(const float* __restrict__ part, float* __restrict__ stats, int nb) {
    int t = threadIdx.x;
    float acc = 0.f;
#pragma unroll 4
    for (int b = 0; b < nb; ++b) acc += part[b * 256 + t];
    stats[t] = acc;
}

extern "C" void kernel_launch(void* const* d_in, const int* in_sizes, int n_in,
                              void* d_out, int out_size, void* d_ws, size_t ws_size,
                              hipStream_t stream) {
    const float* x    = (const float*)d_in[0];
    const int*   ei   = (const int*)d_in[1];
    const float* ew   = (const float*)d_in[2];
    const float* dist = (const float*)d_in[3];
    const float* degf = (const float*)d_in[4];
    const float* W1   = (const float*)d_in[5];
    const float* b1   = (const float*)d_in[6];
    const float* W2   = (const float*)d_in[7];
    const float* b2   = (const float*)d_in[8];
    const float* g1   = (const float*)d_in[9];
    const float* be1  = (const float*)d_in[10];
    const float* g2   = (const float*)d_in[11];
    const float* be2  = (const float*)d_in[12];
    const float* Wd   = (const float*)d_in[13];
    const float* bd   = (const float*)d_in[14];
    const float* Wg   = (const float*)d_in[15];
    const float* bg   = (const float*)d_in[16];
    const float* Wm   = (const float*)d_in[17];
    const float* bm   = (const float*)d_in[18];

    const int IN = 64;
    const int N = in_sizes[0] / IN;   // 100000
    const int E = in_sizes[1] / 2;    // 1600000

    // ws layout (4B words):
    unsigned long long* packed8 = (unsigned long long*)d_ws;         // [8][N] u64
    float* stats  = (float*)d_ws + 16 * (size_t)N;
    int*   flag   = (int*)(stats + 512);
    int*   rowptr = flag + 128;
    int*   cur    = rowptr + N;
    float* dinv   = (float*)(cur + N);
    int*   blktot = (int*)(dinv + N);
    int2*  ecsr   = (int2*)(blktot + 256);
    unsigned int*   h2c  = (unsigned int*)(ecsr + E);                // N*128 bf16
    unsigned short* agg0 = (unsigned short*)(h2c + (size_t)N * 64);  // N*64 bf16
    unsigned short* xb   = agg0 + (size_t)N * 64;                    // N*64 bf16
    short* w1t    = (short*)(xb + (size_t)N * 64);                   // [128][64]
    short* w2t    = w1t + 128 * 64;                                  // [128][128]
    short* wmt    = w2t + 128 * 128;                                 // [128][384]
    float* part   = (float*)(wmt + 128 * 384);                       // [512][256]

    // d_out time-share (bf16 staging, overwritten by final f32 GEMM)
    unsigned short* h1c = (unsigned short*)d_out;                    // N*128 bf16
    unsigned int*   t2  = (unsigned int*)d_out + (size_t)N * 64;     // N*128 bf16 pairs

    hipMemsetAsync(packed8, 0, (16 * (size_t)N + 512) * sizeof(float), stream);

    const int nbE = (E + 255) / 256;
    const int nbN = (N + 255) / 256;
    const int nscan = (N + 1023) / 1024;

    k_flag<<<1, 256, 0, stream>>>(ei, flag);
    k_prep_wt<<<288, 256, 0, stream>>>(W1, W2, Wm, w1t, w2t, wmt);
    k_prep_xb<<<(N * 16 + 255) / 256, 256, 0, stream>>>(x, xb, N * 16);
    k_hist8<<<nbE, 256, 0, stream>>>(ei, ew, flag, packed8, E, N);
    k_scan1<<<nscan, 256, 0, stream>>>(packed8, dinv, rowptr, blktot, N);
    k_scan2<<<1, 256, 0, stream>>>(blktot, nscan);
    k_scan3<<<nbN, 256, 0, stream>>>(rowptr, blktot, cur, N);
    k_scatter<<<nbE * 8, 256, 0, stream>>>(ei, ew, flag, dinv, cur, ecsr, E, N);

    const int nbGe = (N + 127) / 128;
    const int nbG  = (N + 3) / 4;
    const int nbP  = 512;
    const float invN = 1.0f / (float)N;

    // layer 1: agg0 = A_hat @ x; h1c = agg0 @ W1 + b1 (stats1 fused in epilogue)
    k_gather64<<<nbG, 256, 0, stream>>>(xb, ecsr, rowptr, cur, dinv, agg0, N);
    k_gemm<64, 0><<<nbGe, 256, 0, stream>>>(agg0, w1t, stats, nullptr, nullptr, nullptr,
                                            nullptr, nullptr, nullptr, nullptr, nullptr,
                                            b1, h1c, N, invN);

    // layer 2: t2 = BN1ReLU(h1c) @ W2; h2c = A_hat @ t2 + b2; stats2 (two-stage)
    k_gemm<128, 1><<<nbGe, 256, 0, stream>>>(h1c, w2t, stats, g1, be1, nullptr,
                                             nullptr, nullptr, nullptr, nullptr, nullptr,
                                             nullptr, t2, N, invN);
    k_gather128b<<<nbG, 256, 0, stream>>>(t2, ecsr, rowptr, cur, dinv, b2, h2c, N);
    k_bn_partial<<<nbP, 256, 0, stream>>>((const uint4*)h2c, part, N * 16);
    k_bn_reduce<<<1, 256, 0, stream>>>(part, stats + 256, nbP);

    // final: [BN2ReLU(h2c) | relu(dist*Wd+bd) | relu(degf*Wg+bg)] @ Wm + bm -> d_out f32
    k_gemm<384, 2><<<nbGe, 256, 0, stream>>>((const unsigned short*)h2c, wmt, stats + 256,
                                             g2, be2, dist, degf, Wd, bd, Wg, bg,
                                             bm, d_out, N, invN);
}